// Round 5
// baseline (913.876 us; speedup 1.0000x reference)
//
#include <hip/hip_runtime.h>

typedef unsigned short u16;
using bf16x8 = __attribute__((ext_vector_type(8))) short;
using f32x4  = __attribute__((ext_vector_type(4))) float;

__device__ __forceinline__ u16 f2bf(float f) {
  unsigned u = __builtin_bit_cast(unsigned, f);
  u += 0x7fffu + ((u >> 16) & 1u);
  return (u16)(u >> 16);
}
__device__ __forceinline__ float bf2f(u16 h) {
  unsigned u = ((unsigned)h) << 16;
  return __builtin_bit_cast(float, u);
}
__device__ __forceinline__ float f16f(unsigned bits) {
  return (float)__builtin_bit_cast(_Float16, (unsigned short)(bits & 0xffffu));
}
__device__ __forceinline__ u16 f2h(float f) {
  _Float16 h = (_Float16)f;
  return __builtin_bit_cast(unsigned short, h);
}
__device__ __forceinline__ float fast_rcp(float x){ return __builtin_amdgcn_rcpf(x); }
__device__ __forceinline__ float tanh_fast(float x){
  float ax = fabsf(x);
  float e = __expf(-2.f*ax);
  float t = (1.f - e) * fast_rcp(1.f + e);
  return copysignf(t, x);
}
__device__ __forceinline__ float sigmoid_fast(float x){
  return fast_rcp(1.f + __expf(-x));
}
// async global->LDS, 16B per lane (dest = wave-uniform base + lane*16)
__device__ __forceinline__ void gload_lds16(const u16* g, u16* l) {
  __builtin_amdgcn_global_load_lds(
      (const __attribute__((address_space(1))) unsigned*)g,
      (__attribute__((address_space(3))) unsigned*)l, 16, 0, 0);
}

// k-permutation for partial-O / sg / gated / out_w:  k = h*64 + d,  d = dt*16 + col
// stored at k' = h*64 + col*4 + dt  (so attn's per-lane dt-quads are contiguous)
__device__ __forceinline__ int kperm(int k) {
  return (k & ~63) | ((k & 15) << 2) | ((k >> 4) & 3);
}

// ---------------- fp32 -> bf16 convert ----------------
__global__ __launch_bounds__(256) void cvt_bf16(const float* __restrict__ src,
                                                u16* __restrict__ dst, int n){
  int i = (blockIdx.x * 256 + threadIdx.x) * 8;
  if (i >= n) return;
  float4 a = *(const float4*)(src + i);
  float4 b = *(const float4*)(src + i + 4);
  uint4 u;
  u.x = (unsigned)f2bf(a.x) | ((unsigned)f2bf(a.y) << 16);
  u.y = (unsigned)f2bf(a.z) | ((unsigned)f2bf(a.w) << 16);
  u.z = (unsigned)f2bf(b.x) | ((unsigned)f2bf(b.y) << 16);
  u.w = (unsigned)f2bf(b.z) | ((unsigned)f2bf(b.w) << 16);
  *(uint4*)(dst + i) = u;
}

// ---------------- fp32 -> bf16 convert with k-permutation (for out_w) ----------------
__global__ __launch_bounds__(256) void cvt_owb_perm(const float* __restrict__ src,
                                                    u16* __restrict__ dst){
  const int t = blockIdx.x * 256 + threadIdx.x;   // 1024*256 threads
  const int n = t >> 8;
  const int g = t & 255;                          // k' group (4 wide)
  const int h = g >> 4;
  const int c = g & 15;
  const float* s = src + n*1024 + h*64 + c;
  uint2 o;
  o.x = (unsigned)f2bf(s[0])  | ((unsigned)f2bf(s[16]) << 16);
  o.y = (unsigned)f2bf(s[32]) | ((unsigned)f2bf(s[48]) << 16);
  *(uint2*)(dst + n*1024 + g*4) = o;
}

// ---------------- MFMA GEMM: C[m,n] = sum_k A[m,k]*B[n,k] + bias[n] ----------------
// 128x128 tile, 4 waves in 2x2, BK=32. Staging via global_load_lds (width 16).
// LDS layout [qk][row][8] preserved via qk-outer cid mapping (cid = qk*128 + row).
template<int EPI>
__global__ __launch_bounds__(256, 2) void gemm_bt(
    const u16* __restrict__ A, const u16* __restrict__ B, const float* __restrict__ bias,
    u16* __restrict__ oq, u16* __restrict__ ok, u16* __restrict__ ov, u16* __restrict__ og,
    float* __restrict__ outp, int K)
{
  __shared__ u16 a_lds[4*128*8];   // [kquad][row][8]
  __shared__ u16 b_lds[4*128*8];
  const int tid  = threadIdx.x;
  const int lane = tid & 63;
  const int wv   = tid >> 6;
  const int wr   = wv >> 1, wc = wv & 1;
  const int col  = lane & 15, quad = lane >> 4;
  const int m0   = blockIdx.y * 128, n0 = blockIdx.x * 128;
  f32x4 acc[4][4] = {};
  for (int k0 = 0; k0 < K; k0 += 32) {
    __syncthreads();
    #pragma unroll
    for (int s = 0; s < 2; s++) {
      const int cid = s*256 + tid;          // lane-contiguous within each wave
      const int row = cid & 127, qk = cid >> 7;
      gload_lds16(A + (size_t)(m0+row)*K + k0 + qk*8, &a_lds[cid*8]);
      gload_lds16(B + (size_t)(n0+row)*K + k0 + qk*8, &b_lds[cid*8]);
    }
    __syncthreads();                        // drains vmcnt before fragment reads
    bf16x8 af[4], bfr[4];
    #pragma unroll
    for (int mi=0;mi<4;mi++) af[mi]  = *(const bf16x8*)(&a_lds[(quad*128 + wr*64 + mi*16 + col)*8]);
    #pragma unroll
    for (int ni=0;ni<4;ni++) bfr[ni] = *(const bf16x8*)(&b_lds[(quad*128 + wc*64 + ni*16 + col)*8]);
    #pragma unroll
    for (int mi=0;mi<4;mi++)
      #pragma unroll
      for (int ni=0;ni<4;ni++)
        acc[mi][ni] = __builtin_amdgcn_mfma_f32_16x16x32_bf16(af[mi], bfr[ni], acc[mi][ni], 0, 0, 0);
  }
  #pragma unroll
  for (int mi=0;mi<4;mi++) {
    #pragma unroll
    for (int ni=0;ni<4;ni++) {
      #pragma unroll
      for (int r=0;r<4;r++) {
        const int m = m0 + wr*64 + mi*16 + quad*4 + r;   // C row = quad*4+reg
        const int n = n0 + wc*64 + ni*16 + col;          // C col = lane&15
        const float val = acc[mi][ni][r] + bias[n];
        if (EPI == 0) {
          const int idx = m*1024 + (n & 1023);
          const int quarter = n0 >> 10;                  // 128-wide tile: uniform
          if (quarter == 0)      oq[idx] = f2bf(val);
          else if (quarter == 1) ok[idx] = f2bf(val);
          else if (quarter == 2) ov[idx] = f2bf(tanh_fast(val));
          else {
            // sigmoid gate stored k-PERMUTED (consumed linearly by reduce_gate)
            og[m*1024 + kperm(n & 1023)] = f2bf(sigmoid_fast(val));
          }
        } else {
          outp[m*1024 + n] = val;
        }
      }
    }
  }
}

// ---------------- transpose tanh(V): [b,i,h,d] -> [b,h,d,i] ----------------
__global__ __launch_bounds__(256) void vtrans(const u16* __restrict__ vin, u16* __restrict__ vout){
  __shared__ u16 tile[64][68];
  const int bh = blockIdx.y;             // b*16+h
  const int b = bh >> 4, h = bh & 15;
  const int i0 = blockIdx.x * 64;
  const int t = threadIdx.x;
  #pragma unroll
  for (int s=0;s<4;s++){
    int idx = t + 256*s;                 // 1024
    int ti = idx >> 4;                   // 0..63
    int d4 = (idx & 15) * 4;             // 0..60
    uint2 v = *(const uint2*)(vin + ((size_t)((b*1024 + i0 + ti)*16 + h))*64 + d4);
    tile[ti][d4+0] = (u16)(v.x);
    tile[ti][d4+1] = (u16)(v.x >> 16);
    tile[ti][d4+2] = (u16)(v.y);
    tile[ti][d4+3] = (u16)(v.y >> 16);
  }
  __syncthreads();
  #pragma unroll
  for (int s=0;s<4;s++){
    int idx = t + 256*s;
    int d  = idx >> 4;                   // 0..63
    int t4 = (idx & 15) * 4;             // 0..60
    uint2 o;
    o.x = (unsigned)tile[t4+0][d] | ((unsigned)tile[t4+1][d] << 16);
    o.y = (unsigned)tile[t4+2][d] | ((unsigned)tile[t4+3][d] << 16);
    *(uint2*)(vout + ((size_t)((b*16 + h)*64 + d))*1024 + i0 + t4) = o;
  }
}

// ---------------- fused attention (j-split x4, 4 blocks/CU) ----------------
// LDS = 36864 (w_lds) + 4096 (stg) = 40960 B -> exactly 4 blocks/CU (16 waves).
// wout transpose via 1KB-per-wave stage, quad-serialized (4 rounds per r), then
// fully-contiguous 1KB nontemporal stores. Next-t rels/amask/kpm prefetched
// under the PV phase. Partial O fp16, k-permuted (full-line uint2 stores).
__global__ __launch_bounds__(256, 4) void attn_kernel(
    const u16* __restrict__ qb, const u16* __restrict__ kb,
    const u16* __restrict__ vt,
    const float* __restrict__ rels, const float* __restrict__ amask,
    const int* __restrict__ kpm, const float* __restrict__ rbias,
    float* __restrict__ wout,
    u16* __restrict__ o0, u16* __restrict__ o1,
    u16* __restrict__ o2, u16* __restrict__ o3)
{
  __shared__ u16 w_lds[16*16*72];        // [h][i][j(64) pad->72]  (36864 B)
  __shared__ float stg[4][256];          // 1KB per-wave transpose stage (4096 B)
  const int bid = blockIdx.x;
  const int b  = (bid >> 1) & 3;         // XCD swizzle: b -> xcd {2b,2b+1}
  const int it = (bid & 1) | ((bid >> 3) << 1);
  const int i0 = it << 4;
  const int js = blockIdx.y;             // 0..3
  const int t0 = js << 2;                // 4 t-iters per split
  const int t1 = t0 + 4;
  const int tid = threadIdx.x;
  const int lane = tid & 63;
  const int wv  = tid >> 6;
  const int col = lane & 15, quad = lane >> 4;

  float rbv[4][16];                      // wave-uniform -> hopefully SGPRs
  #pragma unroll
  for (int r=0;r<4;r++)
    #pragma unroll
    for (int h=0;h<16;h++)
      rbv[r][h] = rbias[r*16+h];

  f32x4 Oa[4][4] = {};                   // [head-in-wave][d-tile]

  float4 rl4[4]; float mk4[4]; int pd4[4];
  // prologue: issue t0's streaming loads
  {
    const int j0 = (t0 << 6) + (wv << 4);
    #pragma unroll
    for (int r=0; r<4; r++) {
      const int pij = (b*1024 + i0 + quad*4 + r)*1024 + j0 + col;
      rl4[r] = *(const float4*)(rels + (size_t)pij*4);
      mk4[r] = amask[pij];
      pd4[r] = kpm[pij];
    }
  }

  for (int t = t0; t < t1; t++) {
    const int j0b = t << 6;
    const int j0  = j0b + (wv << 4);
    f32x4 sc[16] = {};
    #pragma unroll
    for (int h=0; h<16; h++) {
      #pragma unroll
      for (int c=0; c<2; c++) {
        bf16x8 aq = *(const bf16x8*)(qb + (size_t)(b*1024 + i0 + col)*1024 + h*64 + c*32 + quad*8);
        bf16x8 bk = *(const bf16x8*)(kb + (size_t)(b*1024 + j0 + col)*1024 + h*64 + c*32 + quad*8);
        sc[h] = __builtin_amdgcn_mfma_f32_16x16x32_bf16(aq, bk, sc[h], 0, 0, 0);
      }
    }
    #pragma unroll
    for (int r=0; r<4; r++) {
      const float4 rl = rl4[r];
      float p[16];
      float mx = -1e30f;
      #pragma unroll
      for (int h=0;h<16;h++) {
        float s = sc[h][r];
        s = fmaf(rl.x, rbv[0][h], s);
        s = fmaf(rl.y, rbv[1][h], s);
        s = fmaf(rl.z, rbv[2][h], s);
        s = fmaf(rl.w, rbv[3][h], s);
        s *= 0.125f;                     // D^-0.5
        p[h] = s;
        mx = fmaxf(mx, s);
      }
      float S = 0.f;
      #pragma unroll
      for (int h=0;h<16;h++) { p[h] = __expf(p[h] - mx); S += p[h]; }
      const float scl = pd4[r] ? (__expf(mk4[r]) * fast_rcp(S)) : 0.f;
      #pragma unroll
      for (int h=0;h<16;h++) p[h] *= scl;
      // bf16 copy for PV
      #pragma unroll
      for (int h=0;h<16;h++)
        w_lds[(h*16 + quad*4 + r)*72 + (wv<<4) + col] = f2bf(p[h]);
      // wout transpose: quad-serialized 1KB rounds through per-wave stage
      #pragma unroll
      for (int u=0; u<4; u++) {
        if (quad == u) {
          #pragma unroll
          for (int hg=0; hg<4; hg++) {
            const int ph = hg ^ ((col + (col>>2)) & 3);   // bank-spread swizzle
            f32x4 v4 = { p[4*hg+0], p[4*hg+1], p[4*hg+2], p[4*hg+3] };
            *(f32x4*)&stg[wv][col*16 + ph*4] = v4;
          }
        }
        asm volatile("s_waitcnt lgkmcnt(0)" ::: "memory");
        const int cr = lane >> 2, hr = lane & 3;
        const int pr = hr ^ ((cr + (cr>>2)) & 3);
        f32x4 w4 = *(const f32x4*)&stg[wv][cr*16 + pr*4];
        float* dst = wout + ((size_t)((b*1024 + i0 + u*4 + r)*1024 + j0b + (wv<<4)))*16 + lane*4;
        __builtin_nontemporal_store(w4, (f32x4*)dst);
      }
    }
    __syncthreads();                     // w_lds writes -> PV reads
    // prefetch next t's streaming inputs; PV below covers the latency
    if (t+1 < t1) {
      const int j0n = ((t+1) << 6) + (wv << 4);
      #pragma unroll
      for (int r=0; r<4; r++) {
        const int pij = (b*1024 + i0 + quad*4 + r)*1024 + j0n + col;
        rl4[r] = *(const float4*)(rels + (size_t)pij*4);
        mk4[r] = amask[pij];
        pd4[r] = kpm[pij];
      }
    }
    #pragma unroll
    for (int hh=0; hh<4; hh++) {
      const int h = (wv<<2) + hh;
      #pragma unroll
      for (int c2=0; c2<2; c2++) {
        bf16x8 aw = *(const bf16x8*)(&w_lds[(h*16 + col)*72 + c2*32 + quad*8]);
        #pragma unroll
        for (int dt=0; dt<4; dt++) {
          bf16x8 bv = *(const bf16x8*)(vt + (size_t)((b*16 + h)*64 + dt*16 + col)*1024 + j0b + c2*32 + quad*8);
          Oa[hh][dt] = __builtin_amdgcn_mfma_f32_16x16x32_bf16(aw, bv, Oa[hh][dt], 0, 0, 0);
        }
      }
    }
    __syncthreads();                     // PV reads -> next iter w_lds writes
  }
  // write fp16 partial O (pre-gating), k-PERMUTED: lane stores one uint2 per (hh,r)
  u16* op = (js == 0) ? o0 : ((js == 1) ? o1 : ((js == 2) ? o2 : o3));
  #pragma unroll
  for (int hh=0; hh<4; hh++) {
    const int h = (wv<<2) + hh;
    #pragma unroll
    for (int r=0; r<4; r++) {
      const int i = i0 + quad*4 + r;
      uint2 pk;
      pk.x = (unsigned)f2h(Oa[hh][0][r]) | ((unsigned)f2h(Oa[hh][1][r]) << 16);
      pk.y = (unsigned)f2h(Oa[hh][2][r]) | ((unsigned)f2h(Oa[hh][3][r]) << 16);
      *(uint2*)(op + ((size_t)((b*1024 + i)*16 + h))*64 + col*4) = pk;
    }
  }
}

// ---------------- sum 4 fp16 partials, apply sigmoid gate, emit bf16 ----------------
// All buffers share the SAME k-permuted layout -> fully linear kernel.
// gated aliases o0 byte-for-byte (per-thread read-then-write same bytes) ->
// o0/gated deliberately NOT __restrict__.
__global__ __launch_bounds__(256) void reduce_gate(
    const u16* o0, const u16* __restrict__ o1, const u16* __restrict__ o2,
    const u16* __restrict__ o3,
    const u16* __restrict__ sg, u16* gated)
{
  const int i = (blockIdx.x * 256 + threadIdx.x) * 8;
  uint4 a = *(const uint4*)(o0 + i);
  uint4 b = *(const uint4*)(o1 + i);
  uint4 c = *(const uint4*)(o2 + i);
  uint4 d = *(const uint4*)(o3 + i);
  uint4 s = *(const uint4*)(sg + i);
  const unsigned* ap = (const unsigned*)&a;
  const unsigned* bp = (const unsigned*)&b;
  const unsigned* cp = (const unsigned*)&c;
  const unsigned* dp = (const unsigned*)&d;
  const unsigned* sp = (const unsigned*)&s;
  uint4 r;
  unsigned* rp = (unsigned*)&r;
  #pragma unroll
  for (int k=0;k<4;k++){
    float f0 = (f16f(ap[k])     + f16f(bp[k]))     + (f16f(cp[k])     + f16f(dp[k]));
    float f1 = (f16f(ap[k]>>16) + f16f(bp[k]>>16)) + (f16f(cp[k]>>16) + f16f(dp[k]>>16));
    f0 *= bf2f((u16)(sp[k] & 0xffffu));
    f1 *= bf2f((u16)(sp[k] >> 16));
    rp[k] = (unsigned)f2bf(f0) | ((unsigned)f2bf(f1) << 16);
  }
  *(uint4*)(gated + i) = r;
}

extern "C" void kernel_launch(void* const* d_in, const int* in_sizes, int n_in,
                              void* d_out, int out_size, void* d_ws, size_t ws_size,
                              hipStream_t stream) {
  const float* query  = (const float*)d_in[0];
  const float* rels   = (const float*)d_in[1];
  const float* amask  = (const float*)d_in[2];
  const int*   kpm    = (const int*)d_in[3];
  const float* proj_w = (const float*)d_in[4];
  const float* proj_b = (const float*)d_in[5];
  const float* out_w  = (const float*)d_in[6];
  const float* out_b  = (const float*)d_in[7];
  const float* rbias  = (const float*)d_in[8];

  float* out  = (float*)d_out;
  float* wout = out + (size_t)4*1024*1024;

  char* ws = (char*)d_ws;
  u16* q_b   = (u16*)(ws + ((size_t) 0 << 20));
  u16* k_b   = (u16*)(ws + ((size_t) 8 << 20));
  u16* sg_b  = (u16*)(ws + ((size_t)16 << 20));  // k-permuted
  u16* vth   = (u16*)(ws + ((size_t)24 << 20));
  u16* vt    = (u16*)(ws + ((size_t)32 << 20));
  u16* qryb  = (u16*)(ws + ((size_t)40 << 20));
  u16* pwb   = (u16*)(ws + ((size_t)48 << 20));
  u16* owb   = (u16*)(ws + ((size_t)56 << 20));  // k-permuted
  // fp16 partial-O slices (k-permuted), reusing regions dead by attn launch:
  u16* o0 = qryb;                          // qryb dead after proj GEMM
  u16* o1 = pwb;                           // pwb  dead after proj GEMM
  u16* o2 = vth;                           // vth  dead after vtrans
  u16* o3 = (u16*)out;                     // out region dead until final GEMM (8.4MB < 16MB)
  u16* gated = o0;                         // reduce_gate: read-then-write same bytes

  cvt_bf16<<<2048, 256, 0, stream>>>(query,  qryb, 4*1024*1024);
  cvt_bf16<<<2048, 256, 0, stream>>>(proj_w, pwb,  4*1024*1024);
  cvt_owb_perm<<<1024, 256, 0, stream>>>(out_w, owb);

  gemm_bt<0><<<dim3(32,32), 256, 0, stream>>>(qryb, pwb, proj_b,
                                              q_b, k_b, vth, sg_b, nullptr, 1024);
  vtrans<<<dim3(16,64), 256, 0, stream>>>(vth, vt);
  attn_kernel<<<dim3(256,4), 256, 0, stream>>>(q_b, k_b, vt,
                                               rels, amask, kpm, rbias, wout,
                                               o0, o1, o2, o3);
  reduce_gate<<<2048, 256, 0, stream>>>(o0, o1, o2, o3, sg_b, gated);
  gemm_bt<1><<<dim3(8,32), 256, 0, stream>>>(gated, owb, out_b,
                                             nullptr, nullptr, nullptr, nullptr, out, 1024);
}

// Round 6
// 697.602 us; speedup vs baseline: 1.3100x; 1.3100x over previous
//
#include <hip/hip_runtime.h>

typedef unsigned short u16;
using bf16x8 = __attribute__((ext_vector_type(8))) short;
using f32x4  = __attribute__((ext_vector_type(4))) float;

__device__ __forceinline__ u16 f2bf(float f) {
  unsigned u = __builtin_bit_cast(unsigned, f);
  u += 0x7fffu + ((u >> 16) & 1u);
  return (u16)(u >> 16);
}
__device__ __forceinline__ float bf2f(u16 h) {
  unsigned u = ((unsigned)h) << 16;
  return __builtin_bit_cast(float, u);
}
__device__ __forceinline__ float f16f(unsigned bits) {
  return (float)__builtin_bit_cast(_Float16, (unsigned short)(bits & 0xffffu));
}
__device__ __forceinline__ u16 f2h(float f) {
  _Float16 h = (_Float16)f;
  return __builtin_bit_cast(unsigned short, h);
}
__device__ __forceinline__ float fast_rcp(float x){ return __builtin_amdgcn_rcpf(x); }
__device__ __forceinline__ float tanh_fast(float x){
  float ax = fabsf(x);
  float e = __expf(-2.f*ax);
  float t = (1.f - e) * fast_rcp(1.f + e);
  return copysignf(t, x);
}
__device__ __forceinline__ float sigmoid_fast(float x){
  return fast_rcp(1.f + __expf(-x));
}
// system-scope streaming store: bypasses per-XCD L2 AND MALL (write-once data).
__device__ __forceinline__ void store_sys_x4(f32x4 v, float* p) {
  asm volatile("global_store_dwordx4 %0, %1, off sc0 sc1 nt"
               :: "v"(p), "v"(v) : "memory");
}
// device-scope streaming store: bypasses per-XCD L2, may allocate in MALL.
__device__ __forceinline__ void store_dev_x2(uint2 v, u16* p) {
  asm volatile("global_store_dwordx2 %0, %1, off sc1 nt"
               :: "v"(p), "v"(v) : "memory");
}

// k-permutation for partial-O / sg / gated / out_w:  k = h*64 + d,  d = dt*16 + col
// stored at k' = h*64 + col*4 + dt  (so attn's per-lane dt-quads are contiguous)
__device__ __forceinline__ int kperm(int k) {
  return (k & ~63) | ((k & 15) << 2) | ((k >> 4) & 3);
}

// ---------------- fp32 -> bf16 convert ----------------
__global__ __launch_bounds__(256) void cvt_bf16(const float* __restrict__ src,
                                                u16* __restrict__ dst, int n){
  int i = (blockIdx.x * 256 + threadIdx.x) * 8;
  if (i >= n) return;
  float4 a = *(const float4*)(src + i);
  float4 b = *(const float4*)(src + i + 4);
  uint4 u;
  u.x = (unsigned)f2bf(a.x) | ((unsigned)f2bf(a.y) << 16);
  u.y = (unsigned)f2bf(a.z) | ((unsigned)f2bf(a.w) << 16);
  u.z = (unsigned)f2bf(b.x) | ((unsigned)f2bf(b.y) << 16);
  u.w = (unsigned)f2bf(b.z) | ((unsigned)f2bf(b.w) << 16);
  *(uint4*)(dst + i) = u;
}

// ---------------- fp32 -> bf16 convert with k-permutation (for out_w) ----------------
__global__ __launch_bounds__(256) void cvt_owb_perm(const float* __restrict__ src,
                                                    u16* __restrict__ dst){
  const int t = blockIdx.x * 256 + threadIdx.x;   // 1024*256 threads
  const int n = t >> 8;
  const int g = t & 255;                          // k' group (4 wide)
  const int h = g >> 4;
  const int c = g & 15;
  const float* s = src + n*1024 + h*64 + c;
  uint2 o;
  o.x = (unsigned)f2bf(s[0])  | ((unsigned)f2bf(s[16]) << 16);
  o.y = (unsigned)f2bf(s[32]) | ((unsigned)f2bf(s[48]) << 16);
  *(uint2*)(dst + n*1024 + g*4) = o;
}

// ---------------- MFMA GEMM: C[m,n] = sum_k A[m,k]*B[n,k] + bias[n] ----------------
// 128x128 tile, 4 waves in 2x2, BK=32. Vector-register staging (R4-proven).
template<int EPI>
__global__ __launch_bounds__(256, 2) void gemm_bt(
    const u16* __restrict__ A, const u16* __restrict__ B, const float* __restrict__ bias,
    u16* __restrict__ oq, u16* __restrict__ ok, u16* __restrict__ ov, u16* __restrict__ og,
    float* __restrict__ outp, int K)
{
  __shared__ u16 a_lds[4*128*8];   // [kquad][row][8]
  __shared__ u16 b_lds[4*128*8];
  const int tid  = threadIdx.x;
  const int lane = tid & 63;
  const int wv   = tid >> 6;
  const int wr   = wv >> 1, wc = wv & 1;
  const int col  = lane & 15, quad = lane >> 4;
  const int m0   = blockIdx.y * 128, n0 = blockIdx.x * 128;
  f32x4 acc[4][4] = {};
  for (int k0 = 0; k0 < K; k0 += 32) {
    __syncthreads();
    #pragma unroll
    for (int s = 0; s < 2; s++) {
      int cid = tid + 256*s;
      int row = cid >> 2, qk = cid & 3;
      *(bf16x8*)(&a_lds[(qk*128+row)*8]) = *(const bf16x8*)(A + (m0+row)*K + k0 + qk*8);
      *(bf16x8*)(&b_lds[(qk*128+row)*8]) = *(const bf16x8*)(B + (n0+row)*K + k0 + qk*8);
    }
    __syncthreads();
    bf16x8 af[4], bfr[4];
    #pragma unroll
    for (int mi=0;mi<4;mi++) af[mi]  = *(const bf16x8*)(&a_lds[(quad*128 + wr*64 + mi*16 + col)*8]);
    #pragma unroll
    for (int ni=0;ni<4;ni++) bfr[ni] = *(const bf16x8*)(&b_lds[(quad*128 + wc*64 + ni*16 + col)*8]);
    #pragma unroll
    for (int mi=0;mi<4;mi++)
      #pragma unroll
      for (int ni=0;ni<4;ni++)
        acc[mi][ni] = __builtin_amdgcn_mfma_f32_16x16x32_bf16(af[mi], bfr[ni], acc[mi][ni], 0, 0, 0);
  }
  #pragma unroll
  for (int mi=0;mi<4;mi++) {
    #pragma unroll
    for (int ni=0;ni<4;ni++) {
      #pragma unroll
      for (int r=0;r<4;r++) {
        const int m = m0 + wr*64 + mi*16 + quad*4 + r;   // C row = quad*4+reg
        const int n = n0 + wc*64 + ni*16 + col;          // C col = lane&15
        const float val = acc[mi][ni][r] + bias[n];
        if (EPI == 0) {
          const int idx = m*1024 + (n & 1023);
          const int quarter = n0 >> 10;                  // 128-wide tile: uniform
          if (quarter == 0)      oq[idx] = f2bf(val);
          else if (quarter == 1) ok[idx] = f2bf(val);
          else if (quarter == 2) ov[idx] = f2bf(tanh_fast(val));
          else {
            // sigmoid gate stored k-PERMUTED (consumed linearly by reduce_gate)
            og[m*1024 + kperm(n & 1023)] = f2bf(sigmoid_fast(val));
          }
        } else {
          outp[m*1024 + n] = val;
        }
      }
    }
  }
}

// ---------------- transpose tanh(V): [b,i,h,d] -> [b,h,d,i] ----------------
__global__ __launch_bounds__(256) void vtrans(const u16* __restrict__ vin, u16* __restrict__ vout){
  __shared__ u16 tile[64][68];
  const int bh = blockIdx.y;             // b*16+h
  const int b = bh >> 4, h = bh & 15;
  const int i0 = blockIdx.x * 64;
  const int t = threadIdx.x;
  #pragma unroll
  for (int s=0;s<4;s++){
    int idx = t + 256*s;                 // 1024
    int ti = idx >> 4;                   // 0..63
    int d4 = (idx & 15) * 4;             // 0..60
    uint2 v = *(const uint2*)(vin + ((size_t)((b*1024 + i0 + ti)*16 + h))*64 + d4);
    tile[ti][d4+0] = (u16)(v.x);
    tile[ti][d4+1] = (u16)(v.x >> 16);
    tile[ti][d4+2] = (u16)(v.y);
    tile[ti][d4+3] = (u16)(v.y >> 16);
  }
  __syncthreads();
  #pragma unroll
  for (int s=0;s<4;s++){
    int idx = t + 256*s;
    int d  = idx >> 4;                   // 0..63
    int t4 = (idx & 15) * 4;             // 0..60
    uint2 o;
    o.x = (unsigned)tile[t4+0][d] | ((unsigned)tile[t4+1][d] << 16);
    o.y = (unsigned)tile[t4+2][d] | ((unsigned)tile[t4+3][d] << 16);
    *(uint2*)(vout + ((size_t)((b*16 + h)*64 + d))*1024 + i0 + t4) = o;
  }
}

// ---------------- fused attention (j-split x3, R4 structure) ----------------
// wout: LDS transpose -> 1KB contiguous stores, SYSTEM-scope streaming (sc0 sc1 nt)
//   -> bypasses per-XCD L2 and MALL: stops the 268MB/iter stream from evicting
//      the K/vt/Q lines that co-XCD blocks share (the R4 excess-FETCH mechanism).
// rels/amask/kpm loaded nontemporal (read-once streams, evict-first).
// Partial O fp16, k-permuted, device-scope streaming store (skip L2, keep MALL).
__global__ __launch_bounds__(256, 3) void attn_kernel(
    const u16* __restrict__ qb, const u16* __restrict__ kb,
    const u16* __restrict__ vt,
    const float* __restrict__ rels, const float* __restrict__ amask,
    const int* __restrict__ kpm, const float* __restrict__ rbias,
    float* __restrict__ wout,
    u16* __restrict__ o0, u16* __restrict__ o1, u16* __restrict__ o2)
{
  __shared__ u16 w_lds[16*16*72];        // [h][i][j(64) pad->72]  (36864 B)
  __shared__ float stageF[4][1024];      // per-wave fp32 P transpose staging (16384 B)
  const int bid = blockIdx.x;
  const int b  = (bid >> 1) & 3;         // XCD swizzle: b -> xcd {2b,2b+1}
  const int it = (bid & 1) | ((bid >> 3) << 1);
  const int i0 = it << 4;
  const int js = blockIdx.y;             // 0..2
  const int t0 = js*5 + (js > 0);        // 0,6,11
  const int t1 = t0 + (js == 0 ? 6 : 5); // 6,11,16
  const int tid = threadIdx.x;
  const int lane = tid & 63;
  const int wv  = tid >> 6;
  const int col = lane & 15, quad = lane >> 4;

  float rbv[4][16];                      // wave-uniform -> hopefully SGPRs
  #pragma unroll
  for (int r=0;r<4;r++)
    #pragma unroll
    for (int h=0;h<16;h++)
      rbv[r][h] = rbias[r*16+h];

  f32x4 Oa[4][4] = {};                   // [head-in-wave][d-tile]

  for (int t = t0; t < t1; t++) {
    const int j0b = t << 6;
    const int j0  = j0b + (wv << 4);
    // issue streaming HBM loads early (nontemporal): QK phase covers their latency
    f32x4 rl4[4]; float mk4[4]; int pd4[4];
    #pragma unroll
    for (int r=0; r<4; r++) {
      const int pij = (b*1024 + i0 + quad*4 + r)*1024 + j0 + col;
      rl4[r] = __builtin_nontemporal_load((const f32x4*)(rels + (size_t)pij*4));
      mk4[r] = __builtin_nontemporal_load(amask + pij);
      pd4[r] = __builtin_nontemporal_load(kpm + pij);
    }
    f32x4 sc[16] = {};
    #pragma unroll
    for (int h=0; h<16; h++) {
      #pragma unroll
      for (int c=0; c<2; c++) {
        bf16x8 aq = *(const bf16x8*)(qb + (size_t)(b*1024 + i0 + col)*1024 + h*64 + c*32 + quad*8);
        bf16x8 bk = *(const bf16x8*)(kb + (size_t)(b*1024 + j0 + col)*1024 + h*64 + c*32 + quad*8);
        sc[h] = __builtin_amdgcn_mfma_f32_16x16x32_bf16(aq, bk, sc[h], 0, 0, 0);
      }
    }
    #pragma unroll
    for (int r=0; r<4; r++) {
      const f32x4 rl = rl4[r];
      float p[16];
      float mx = -1e30f;
      #pragma unroll
      for (int h=0;h<16;h++) {
        float s = sc[h][r];
        s = fmaf(rl[0], rbv[0][h], s);
        s = fmaf(rl[1], rbv[1][h], s);
        s = fmaf(rl[2], rbv[2][h], s);
        s = fmaf(rl[3], rbv[3][h], s);
        s *= 0.125f;                     // D^-0.5
        p[h] = s;
        mx = fmaxf(mx, s);
      }
      float S = 0.f;
      #pragma unroll
      for (int h=0;h<16;h++) { p[h] = __expf(p[h] - mx); S += p[h]; }
      const float scl = pd4[r] ? (__expf(mk4[r]) * fast_rcp(S)) : 0.f;
      #pragma unroll
      for (int h=0;h<16;h++) p[h] *= scl;
      // stage fp32 P into LDS (XOR-swizzled h-groups: bank-balanced)
      #pragma unroll
      for (int hg=0; hg<4; hg++) {
        const int ph = hg ^ ((col + quad) & 3);
        f32x4 v4 = { p[4*hg+0], p[4*hg+1], p[4*hg+2], p[4*hg+3] };
        *(f32x4*)&stageF[wv][quad*256 + col*16 + ph*4] = v4;
      }
      // bf16 copy for PV
      #pragma unroll
      for (int h=0;h<16;h++)
        w_lds[(h*16 + quad*4 + r)*72 + (wv<<4) + col] = f2bf(p[h]);
      // wave-internal LDS transpose complete -> coalesced full-line system stores
      asm volatile("s_waitcnt lgkmcnt(0)" ::: "memory");
      const int rcol = lane >> 2, rhg = lane & 3;
      #pragma unroll
      for (int qt=0; qt<4; qt++) {
        const int ph = rhg ^ ((rcol + qt) & 3);
        f32x4 w4 = *(const f32x4*)&stageF[wv][qt*256 + rcol*16 + ph*4];
        float* dst = wout + ((size_t)((b*1024 + i0 + qt*4 + r)*1024 + j0b + (wv<<4)))*16 + lane*4;
        store_sys_x4(w4, dst);
      }
    }
    __syncthreads();                     // w_lds writes -> PV reads
    #pragma unroll
    for (int hh=0; hh<4; hh++) {
      const int h = (wv<<2) + hh;
      #pragma unroll
      for (int c2=0; c2<2; c2++) {
        bf16x8 aw = *(const bf16x8*)(&w_lds[(h*16 + col)*72 + c2*32 + quad*8]);
        #pragma unroll
        for (int dt=0; dt<4; dt++) {
          bf16x8 bv = *(const bf16x8*)(vt + (size_t)((b*16 + h)*64 + dt*16 + col)*1024 + j0b + c2*32 + quad*8);
          Oa[hh][dt] = __builtin_amdgcn_mfma_f32_16x16x32_bf16(aw, bv, Oa[hh][dt], 0, 0, 0);
        }
      }
    }
    __syncthreads();                     // PV reads -> next iter w_lds writes
  }
  // write fp16 partial O (pre-gating), k-PERMUTED: lane stores one uint2 per (hh,r)
  // -> 16 lanes/quad cover a full contiguous 128B line. Device-scope streaming.
  u16* op = (js == 0) ? o0 : ((js == 1) ? o1 : o2);
  #pragma unroll
  for (int hh=0; hh<4; hh++) {
    const int h = (wv<<2) + hh;
    #pragma unroll
    for (int r=0; r<4; r++) {
      const int i = i0 + quad*4 + r;
      uint2 pk;
      pk.x = (unsigned)f2h(Oa[hh][0][r]) | ((unsigned)f2h(Oa[hh][1][r]) << 16);
      pk.y = (unsigned)f2h(Oa[hh][2][r]) | ((unsigned)f2h(Oa[hh][3][r]) << 16);
      store_dev_x2(pk, op + ((size_t)((b*1024 + i)*16 + h))*64 + col*4);
    }
  }
}

// ---------------- sum 3 fp16 partials, apply sigmoid gate, emit bf16 ----------------
// All buffers share the SAME k-permuted layout -> fully linear kernel.
// gated aliases o0 byte-for-byte (per-thread read-then-write same bytes) ->
// o0/gated deliberately NOT __restrict__.
__global__ __launch_bounds__(256) void reduce_gate(
    const u16* o0, const u16* __restrict__ o1, const u16* __restrict__ o2,
    const u16* __restrict__ sg, u16* gated)
{
  const int i = (blockIdx.x * 256 + threadIdx.x) * 8;
  uint4 a = *(const uint4*)(o0 + i);
  uint4 b = *(const uint4*)(o1 + i);
  uint4 c = *(const uint4*)(o2 + i);
  uint4 s = *(const uint4*)(sg + i);
  const unsigned* ap = (const unsigned*)&a;
  const unsigned* bp = (const unsigned*)&b;
  const unsigned* cp = (const unsigned*)&c;
  const unsigned* sp = (const unsigned*)&s;
  uint4 r;
  unsigned* rp = (unsigned*)&r;
  #pragma unroll
  for (int k=0;k<4;k++){
    float f0 = f16f(ap[k]) + f16f(bp[k]) + f16f(cp[k]);
    float f1 = f16f(ap[k]>>16) + f16f(bp[k]>>16) + f16f(cp[k]>>16);
    f0 *= bf2f((u16)(sp[k] & 0xffffu));
    f1 *= bf2f((u16)(sp[k] >> 16));
    rp[k] = (unsigned)f2bf(f0) | ((unsigned)f2bf(f1) << 16);
  }
  *(uint4*)(gated + i) = r;
}

extern "C" void kernel_launch(void* const* d_in, const int* in_sizes, int n_in,
                              void* d_out, int out_size, void* d_ws, size_t ws_size,
                              hipStream_t stream) {
  const float* query  = (const float*)d_in[0];
  const float* rels   = (const float*)d_in[1];
  const float* amask  = (const float*)d_in[2];
  const int*   kpm    = (const int*)d_in[3];
  const float* proj_w = (const float*)d_in[4];
  const float* proj_b = (const float*)d_in[5];
  const float* out_w  = (const float*)d_in[6];
  const float* out_b  = (const float*)d_in[7];
  const float* rbias  = (const float*)d_in[8];

  float* out  = (float*)d_out;
  float* wout = out + (size_t)4*1024*1024;

  char* ws = (char*)d_ws;
  u16* q_b   = (u16*)(ws + ((size_t) 0 << 20));
  u16* k_b   = (u16*)(ws + ((size_t) 8 << 20));
  u16* sg_b  = (u16*)(ws + ((size_t)16 << 20));  // k-permuted
  u16* vth   = (u16*)(ws + ((size_t)24 << 20));
  u16* vt    = (u16*)(ws + ((size_t)32 << 20));
  u16* qryb  = (u16*)(ws + ((size_t)40 << 20));
  u16* pwb   = (u16*)(ws + ((size_t)48 << 20));
  u16* owb   = (u16*)(ws + ((size_t)56 << 20));  // k-permuted
  // fp16 partial-O slices (k-permuted), reusing regions dead by attn launch:
  u16* o0 = qryb;                          // qryb dead after proj GEMM
  u16* o1 = pwb;                           // pwb  dead after proj GEMM
  u16* o2 = vth;                           // vth  dead after vtrans
  u16* gated = o0;                         // reduce_gate: read-then-write same bytes

  cvt_bf16<<<2048, 256, 0, stream>>>(query,  qryb, 4*1024*1024);
  cvt_bf16<<<2048, 256, 0, stream>>>(proj_w, pwb,  4*1024*1024);
  cvt_owb_perm<<<1024, 256, 0, stream>>>(out_w, owb);

  gemm_bt<0><<<dim3(32,32), 256, 0, stream>>>(qryb, pwb, proj_b,
                                              q_b, k_b, vth, sg_b, nullptr, 1024);
  vtrans<<<dim3(16,64), 256, 0, stream>>>(vth, vt);
  attn_kernel<<<dim3(256,3), 256, 0, stream>>>(q_b, k_b, vt,
                                               rels, amask, kpm, rbias, wout,
                                               o0, o1, o2);
  reduce_gate<<<2048, 256, 0, stream>>>(o0, o1, o2, sg_b, gated);
  gemm_bt<1><<<dim3(8,32), 256, 0, stream>>>(gated, owb, out_b,
                                             nullptr, nullptr, nullptr, nullptr, out, 1024);
}